// Round 5
// baseline (631.093 us; speedup 1.0000x reference)
//
#include <hip/hip_runtime.h>
#include <hip/hip_cooperative_groups.h>

namespace cg = cooperative_groups;

#define F 128
#define TR 64    // GEMM row tile
#define KC 32    // GEMM k chunk
#define LDA 36   // sA leading dim: float4-aligned, 2-way read aliasing (free)
#define LDW 160  // sW row: 8 chunks x 20 floats (distinct banks per g)

// ============ fused CSR build (cooperative): ============
// phase0: zero counts + dtype detect + optional x->bf16 convert
// phase1: histogram of dst
// phase2: block-chunk exclusive scan (locoff + cursor + blocksums)
// phase3: scan of blocksums (block 0, chunked with carry)
// phase4: position pass -> csr_src
__global__ __launch_bounds__(256, 4) void csr_build_kernel(
    const int* __restrict__ ei, const float* __restrict__ x,
    int* __restrict__ flag, int* __restrict__ counts,
    int* __restrict__ locoff, int* __restrict__ cursor,
    int* __restrict__ blocksums, int* __restrict__ blockoffs,
    int* __restrict__ csr_src, unsigned int* __restrict__ xh,
    int N, int E, int nblk, int do_bf16)
{
    cg::grid_group grid = cg::this_grid();
    const int T = gridDim.x * 256;
    const int tid = blockIdx.x * 256 + threadIdx.x;
    __shared__ int sh[256];
    __shared__ int carry_s;

    // ---- phase 0 ----
    for (int i = tid; i < N; i += T) counts[i] = 0;
    if (tid == 0) {
        int or_hi = ei[1] | ei[3] | ei[5] | ei[7] | ei[9] | ei[11] | ei[13] | ei[15];
        *flag = (or_hi == 0) ? 1 : 0;
    }
    if (do_bf16) {
        const float2* x2 = reinterpret_cast<const float2*>(x);
        int M = N * (F / 2);
        for (int j = tid; j < M; j += T) {
            float2 v = x2[j];
            unsigned ux = __float_as_uint(v.x);
            unsigned uy = __float_as_uint(v.y);
            unsigned lo = (ux + 0x7fffu + ((ux >> 16) & 1u)) >> 16;  // RTNE
            unsigned hi = (uy + 0x7fffu + ((uy >> 16) & 1u)) >> 16;
            xh[j] = lo | (hi << 16);
        }
    }
    grid.sync();

    // ---- phase 1: histogram ----
    const int is64 = *flag;
    if (is64) {
        const int2* e2 = reinterpret_cast<const int2*>(ei);
        for (int e = tid; e < E; e += T)
            atomicAdd(&counts[e2[(size_t)E + e].x], 1);
    } else {
        for (int e = tid; e < E; e += T)
            atomicAdd(&counts[ei[E + e]], 1);
    }
    grid.sync();

    // ---- phase 2: per-chunk exclusive scan ----
    for (int c = blockIdx.x; c < nblk; c += gridDim.x) {
        int t = threadIdx.x;
        int i = c * 256 + t;
        int v = (i < N) ? counts[i] : 0;
        sh[t] = v;
        __syncthreads();
        int inc = v;
        #pragma unroll
        for (int ofs = 1; ofs < 256; ofs <<= 1) {
            int add = (t >= ofs) ? sh[t - ofs] : 0;
            __syncthreads();
            inc += add;
            sh[t] = inc;
            __syncthreads();
        }
        if (i < N) { locoff[i] = inc - v; cursor[i] = inc - v; }
        if (t == 255) blocksums[c] = inc;
        __syncthreads();
    }
    grid.sync();

    // ---- phase 3: scan blocksums (block 0 only, chunked with carry) ----
    if (blockIdx.x == 0) {
        int t = threadIdx.x;
        if (t == 0) carry_s = 0;
        __syncthreads();
        for (int base = 0; base < nblk; base += 256) {
            int idx = base + t;
            int v = (idx < nblk) ? blocksums[idx] : 0;
            sh[t] = v;
            __syncthreads();
            int inc = v;
            #pragma unroll
            for (int ofs = 1; ofs < 256; ofs <<= 1) {
                int add = (t >= ofs) ? sh[t - ofs] : 0;
                __syncthreads();
                inc += add;
                sh[t] = inc;
                __syncthreads();
            }
            if (idx < nblk) blockoffs[idx] = inc - v + carry_s;
            __syncthreads();
            if (t == 255) carry_s += inc;
            __syncthreads();
        }
    }
    grid.sync();

    // ---- phase 4: position pass ----
    if (is64) {
        const int2* e2 = reinterpret_cast<const int2*>(ei);
        for (int e = tid; e < E; e += T) {
            int s = e2[e].x;
            int d = e2[(size_t)E + e].x;
            int pos = atomicAdd(&cursor[d], 1) + blockoffs[d >> 8];
            csr_src[pos] = s;
        }
    } else {
        for (int e = tid; e < E; e += T) {
            int s = ei[e];
            int d = ei[E + e];
            int pos = atomicAdd(&cursor[d], 1) + blockoffs[d >> 8];
            csr_src[pos] = s;
        }
    }
}

// ---------- bf16 gather: one node/wave; 2 half-waves x 2 unroll = 4 edges ----
__device__ __forceinline__ float4 bf16x4_to_f4(uint2 u)
{
    float4 f;
    f.x = __uint_as_float(u.x << 16);
    f.y = __uint_as_float(u.x & 0xffff0000u);
    f.z = __uint_as_float(u.y << 16);
    f.w = __uint_as_float(u.y & 0xffff0000u);
    return f;
}

__global__ __launch_bounds__(256) void gather_bf16_kernel(
    const unsigned int* __restrict__ xh, const int* __restrict__ locoff,
    const int* __restrict__ blockoffs, const int* __restrict__ counts,
    const int* __restrict__ csr_src, float* __restrict__ agg, int N)
{
    int node = blockIdx.x * 4 + (threadIdx.x >> 6);
    if (node >= N) return;
    int lane = threadIdx.x & 63;
    int half = lane >> 5;
    int col = lane & 31;              // uint2 column: feats 4c..4c+3
    int start = locoff[node] + blockoffs[node >> 8];
    int deg = counts[node];

    const uint2* x2 = reinterpret_cast<const uint2*>(xh);
    float4 a0 = make_float4(0.f, 0.f, 0.f, 0.f);
    float4 a1 = make_float4(0.f, 0.f, 0.f, 0.f);

    for (int base = 0; base < deg; base += 64) {
        int rem = deg - base; if (rem > 64) rem = 64;
        int sv = (lane < rem) ? csr_src[start + base + lane] : 0;
        int i = 0;
        for (; i + 3 < rem; i += 4) {
            int e0 = __shfl(sv, i + half);
            int e1 = __shfl(sv, i + 2 + half);
            float4 v0 = bf16x4_to_f4(x2[(size_t)e0 * 32 + col]);
            float4 v1 = bf16x4_to_f4(x2[(size_t)e1 * 32 + col]);
            a0.x += v0.x; a0.y += v0.y; a0.z += v0.z; a0.w += v0.w;
            a1.x += v1.x; a1.y += v1.y; a1.z += v1.z; a1.w += v1.w;
        }
        for (; i + 1 < rem; i += 2) {
            int e0 = __shfl(sv, i + half);
            float4 v0 = bf16x4_to_f4(x2[(size_t)e0 * 32 + col]);
            a0.x += v0.x; a0.y += v0.y; a0.z += v0.z; a0.w += v0.w;
        }
        if (i < rem) {
            int e0 = __shfl(sv, i);
            if (half == 0) {
                float4 v = bf16x4_to_f4(x2[(size_t)e0 * 32 + col]);
                a0.x += v.x; a0.y += v.y; a0.z += v.z; a0.w += v.w;
            }
        }
    }
    a0.x += a1.x; a0.y += a1.y; a0.z += a1.z; a0.w += a1.w;
    a0.x += __shfl_xor(a0.x, 32);
    a0.y += __shfl_xor(a0.y, 32);
    a0.z += __shfl_xor(a0.z, 32);
    a0.w += __shfl_xor(a0.w, 32);
    if (half == 0)
        reinterpret_cast<float4*>(agg)[(size_t)node * 32 + col] = a0;
}

// ---------- fp32 gather (fallback when ws can't hold bf16 table) ----------
__global__ __launch_bounds__(256) void gather_f32_kernel(
    const float* __restrict__ x, const int* __restrict__ locoff,
    const int* __restrict__ blockoffs, const int* __restrict__ counts,
    const int* __restrict__ csr_src, float* __restrict__ agg, int N)
{
    int node = blockIdx.x * 4 + (threadIdx.x >> 6);
    if (node >= N) return;
    int lane = threadIdx.x & 63;
    int half = lane >> 5;
    int col = lane & 31;
    int start = locoff[node] + blockoffs[node >> 8];
    int deg = counts[node];

    const float4* x4 = reinterpret_cast<const float4*>(x);
    float4 a0 = make_float4(0.f, 0.f, 0.f, 0.f);
    float4 a1 = make_float4(0.f, 0.f, 0.f, 0.f);

    for (int base = 0; base < deg; base += 64) {
        int rem = deg - base; if (rem > 64) rem = 64;
        int sv = (lane < rem) ? csr_src[start + base + lane] : 0;
        int i = 0;
        for (; i + 3 < rem; i += 4) {
            int e0 = __shfl(sv, i + half);
            int e1 = __shfl(sv, i + 2 + half);
            float4 v0 = x4[(size_t)e0 * 32 + col];
            float4 v1 = x4[(size_t)e1 * 32 + col];
            a0.x += v0.x; a0.y += v0.y; a0.z += v0.z; a0.w += v0.w;
            a1.x += v1.x; a1.y += v1.y; a1.z += v1.z; a1.w += v1.w;
        }
        for (; i + 1 < rem; i += 2) {
            int e0 = __shfl(sv, i + half);
            float4 v0 = x4[(size_t)e0 * 32 + col];
            a0.x += v0.x; a0.y += v0.y; a0.z += v0.z; a0.w += v0.w;
        }
        if (i < rem) {
            int e0 = __shfl(sv, i);
            if (half == 0) {
                float4 v = x4[(size_t)e0 * 32 + col];
                a0.x += v.x; a0.y += v.y; a0.z += v.z; a0.w += v.w;
            }
        }
    }
    a0.x += a1.x; a0.y += a1.y; a0.z += a1.z; a0.w += a1.w;
    a0.x += __shfl_xor(a0.x, 32);
    a0.y += __shfl_xor(a0.y, 32);
    a0.z += __shfl_xor(a0.z, 32);
    a0.w += __shfl_xor(a0.w, 32);
    if (half == 0)
        reinterpret_cast<float4*>(agg)[(size_t)node * 32 + col] = a0;
}

// ---------- minimal fallback: dtype detect + atomic scatter ----------
__global__ void detect_kernel(const int* __restrict__ ei, int* __restrict__ flag)
{
    if (threadIdx.x == 0 && blockIdx.x == 0) {
        int or_hi = ei[1] | ei[3] | ei[5] | ei[7] | ei[9] | ei[11] | ei[13] | ei[15];
        *flag = (or_hi == 0) ? 1 : 0;
    }
}

__global__ __launch_bounds__(256) void scatter_kernel(
    const float* __restrict__ x, const int* __restrict__ ei,
    const int* __restrict__ flag_p, float* __restrict__ agg, int E)
{
    int tid = blockIdx.x * 256 + threadIdx.x;
    int e = tid >> 5;
    if (e >= E) return;
    int c = (tid & 31) << 2;
    int s, d;
    if (*flag_p) {
        s = reinterpret_cast<const int2*>(ei)[e].x;
        d = reinterpret_cast<const int2*>(ei)[(size_t)E + e].x;
    } else {
        s = ei[e];
        d = ei[E + e];
    }
    float4 v = *reinterpret_cast<const float4*>(x + (size_t)s * F + c);
    float* o = agg + (size_t)d * F + c;
    unsafeAtomicAdd(o + 0, v.x);
    unsafeAtomicAdd(o + 1, v.y);
    unsafeAtomicAdd(o + 2, v.z);
    unsafeAtomicAdd(o + 3, v.w);
}

// ---------- in-place GEMM: io = io @ W + bias ----------
__global__ __launch_bounds__(256) void gemm_kernel(
    float* __restrict__ io, const float* __restrict__ W,
    const float* __restrict__ bias, int N)
{
    __shared__ float sA[TR * LDA];
    __shared__ float sW[KC * LDW];
    const int t = threadIdx.x;
    const int row0 = blockIdx.x * TR;
    const int g = t & 7;
    const int r = t >> 3;

    float acc[2][16];
    #pragma unroll
    for (int i = 0; i < 2; ++i)
        #pragma unroll
        for (int j = 0; j < 16; ++j) acc[i][j] = 0.0f;

    for (int kc = 0; kc < F; kc += KC) {
        #pragma unroll
        for (int u = 0; u < 2; ++u) {
            int idx = u * 256 + t;
            int row = idx >> 3;
            int k4 = (idx & 7) * 4;
            int grow = row0 + row;
            float4 v = (grow < N)
                ? *reinterpret_cast<const float4*>(io + (size_t)grow * F + kc + k4)
                : make_float4(0.f, 0.f, 0.f, 0.f);
            *reinterpret_cast<float4*>(&sA[row * LDA + k4]) = v;
        }
        #pragma unroll
        for (int u = 0; u < 4; ++u) {
            int idx = u * 256 + t;
            int kk = idx >> 5;
            int f4 = (idx & 31) * 4;
            float4 v = *reinterpret_cast<const float4*>(W + (size_t)(kc + kk) * F + f4);
            int chunk = f4 >> 4;
            int within = f4 & 15;
            *reinterpret_cast<float4*>(&sW[kk * LDW + chunk * 20 + within]) = v;
        }
        __syncthreads();

        #pragma unroll 8
        for (int kk = 0; kk < KC; ++kk) {
            const float* wp = &sW[kk * LDW + g * 20];
            const float4 w0 = *reinterpret_cast<const float4*>(wp + 0);
            const float4 w1 = *reinterpret_cast<const float4*>(wp + 4);
            const float4 w2 = *reinterpret_cast<const float4*>(wp + 8);
            const float4 w3 = *reinterpret_cast<const float4*>(wp + 12);
            #pragma unroll
            for (int i = 0; i < 2; ++i) {
                const float xv = sA[(r * 2 + i) * LDA + kk];
                acc[i][0]  += xv * w0.x;  acc[i][1]  += xv * w0.y;
                acc[i][2]  += xv * w0.z;  acc[i][3]  += xv * w0.w;
                acc[i][4]  += xv * w1.x;  acc[i][5]  += xv * w1.y;
                acc[i][6]  += xv * w1.z;  acc[i][7]  += xv * w1.w;
                acc[i][8]  += xv * w2.x;  acc[i][9]  += xv * w2.y;
                acc[i][10] += xv * w2.z;  acc[i][11] += xv * w2.w;
                acc[i][12] += xv * w3.x;  acc[i][13] += xv * w3.y;
                acc[i][14] += xv * w3.z;  acc[i][15] += xv * w3.w;
            }
        }
        __syncthreads();
    }

    float bv[16];
    #pragma unroll
    for (int j = 0; j < 16; ++j) bv[j] = bias[g * 16 + j];
    #pragma unroll
    for (int i = 0; i < 2; ++i) {
        int row = row0 + r * 2 + i;
        if (row < N) {
            float* o = io + (size_t)row * F + g * 16;
            #pragma unroll
            for (int j4 = 0; j4 < 4; ++j4) {
                float4 v;
                v.x = acc[i][j4 * 4 + 0] + bv[j4 * 4 + 0];
                v.y = acc[i][j4 * 4 + 1] + bv[j4 * 4 + 1];
                v.z = acc[i][j4 * 4 + 2] + bv[j4 * 4 + 2];
                v.w = acc[i][j4 * 4 + 3] + bv[j4 * 4 + 3];
                *reinterpret_cast<float4*>(o + j4 * 4) = v;
            }
        }
    }
}

extern "C" void kernel_launch(void* const* d_in, const int* in_sizes, int n_in,
                              void* d_out, int out_size, void* d_ws, size_t ws_size,
                              hipStream_t stream) {
    const float* x  = (const float*)d_in[0];
    const int*   ei = (const int*)d_in[1];
    const float* W2 = (const float*)d_in[5];
    const float* b2 = (const float*)d_in[6];
    float* out = (float*)d_out;

    int N = in_sizes[0] / F;   // 50000
    int E = in_sizes[2];       // 600000
    int nblk = (N + 255) / 256;

    int* ws = (int*)d_ws;
    int* flag      = ws;                  // [16]
    int* counts    = flag + 16;           // [N]
    int* locoff    = counts + N;          // [N]
    int* cursor    = locoff + N;          // [N]
    int* blocksums = cursor + N;          // [nblk]
    int* blockoffs = blocksums + nblk;    // [nblk]
    int* csr_src   = blockoffs + nblk;    // [E]
    unsigned int* xh = (unsigned int*)(csr_src + E);  // [N*F/2] bf16 table
    size_t need_f32  = (size_t)(16 + 3 * N + 2 * nblk + E) * sizeof(int);
    size_t need_bf16 = need_f32 + (size_t)N * (F / 2) * sizeof(int);

    if (ws_size >= need_f32) {
        int do_bf16 = (ws_size >= need_bf16) ? 1 : 0;

        // size cooperative grid: min(1024, maxBlocksPerCU * numCUs)
        int maxb = 0, cus = 0, dev = 0;
        (void)hipGetDevice(&dev);
        if (hipDeviceGetAttribute(&cus, hipDeviceAttributeMultiprocessorCount, dev)
            != hipSuccess || cus <= 0) cus = 256;
        if (hipOccupancyMaxActiveBlocksPerMultiprocessor(&maxb, csr_build_kernel, 256, 0)
            != hipSuccess || maxb <= 0) maxb = 1;
        int grid = maxb * cus;
        if (grid > 1024) grid = 1024;
        if (grid < 1) grid = 256;

        void* args[] = {
            (void*)&ei, (void*)&x, (void*)&flag, (void*)&counts, (void*)&locoff,
            (void*)&cursor, (void*)&blocksums, (void*)&blockoffs, (void*)&csr_src,
            (void*)&xh, (void*)&N, (void*)&E, (void*)&nblk, (void*)&do_bf16
        };
        hipLaunchCooperativeKernel((void*)csr_build_kernel, dim3(grid), dim3(256),
                                   args, 0, stream);

        if (do_bf16)
            gather_bf16_kernel<<<(N + 3) / 4, 256, 0, stream>>>(
                xh, locoff, blockoffs, counts, csr_src, out, N);
        else
            gather_f32_kernel<<<(N + 3) / 4, 256, 0, stream>>>(
                x, locoff, blockoffs, counts, csr_src, out, N);
    } else {
        detect_kernel<<<1, 64, 0, stream>>>(ei, flag);
        hipMemsetAsync(out, 0, (size_t)N * F * sizeof(float), stream);
        int sblocks = (E * 32 + 255) / 256;
        scatter_kernel<<<sblocks, 256, 0, stream>>>(x, ei, flag, out, E);
    }

    gemm_kernel<<<(N + TR - 1) / TR, 256, 0, stream>>>(out, W2, b2, N);
}

// Round 6
// 187.324 us; speedup vs baseline: 3.3690x; 3.3690x over previous
//
#include <hip/hip_runtime.h>

#define F 128
#define CAP 64   // bucket capacity per node (deg~Poisson(12); overflow path below)
#define TR 64    // GEMM row tile
#define KC 32    // GEMM k chunk
#define LDA 36   // sA leading dim: float4-aligned
#define LDW 160  // sW row: 8 chunks x 20 floats (distinct banks per g)

// ---------- init: convert x->bf16 (optional) + zero array + dtype detect ----
__global__ __launch_bounds__(256) void init_kernel(
    const int* __restrict__ ei, const float* __restrict__ x,
    int* __restrict__ flag, int* __restrict__ zero_arr,
    unsigned int* __restrict__ xh, int N, int M)
{
    int i = blockIdx.x * 256 + threadIdx.x;
    if (i < M) {
        float2 v = reinterpret_cast<const float2*>(x)[i];
        unsigned ux = __float_as_uint(v.x);
        unsigned uy = __float_as_uint(v.y);
        unsigned lo = (ux + 0x7fffu + ((ux >> 16) & 1u)) >> 16;  // RTNE
        unsigned hi = (uy + 0x7fffu + ((uy >> 16) & 1u)) >> 16;
        xh[i] = lo | (hi << 16);
    }
    if (i < N) zero_arr[i] = 0;
    if (i == 0) {
        int or_hi = ei[1] | ei[3] | ei[5] | ei[7] | ei[9] | ei[11] | ei[13] | ei[15];
        *flag = (or_hi == 0) ? 1 : 0;
    }
}

__device__ __forceinline__ void load_edge(const int* __restrict__ ei, int is64,
                                          int E, int e, int& s, int& d)
{
    if (is64) {
        s = reinterpret_cast<const int2*>(ei)[e].x;
        d = reinterpret_cast<const int2*>(ei)[(size_t)E + e].x;
    } else {
        s = ei[e];
        d = ei[E + e];
    }
}

// ---------- bucketed position pass: csr_src[d*CAP + slot] = s ----------
__global__ __launch_bounds__(256) void position_bucket_kernel(
    const int* __restrict__ ei, const int* __restrict__ flag_p,
    int* __restrict__ cursor, int* __restrict__ csr_src, int E)
{
    int e = blockIdx.x * 256 + threadIdx.x;
    if (e >= E) return;
    int s, d;
    load_edge(ei, *flag_p, E, e, s, d);
    int slot = atomicAdd(&cursor[d], 1);
    if (slot < CAP) csr_src[d * CAP + slot] = s;
}

__device__ __forceinline__ float4 bf16x4_to_f4(uint2 u)
{
    float4 f;
    f.x = __uint_as_float(u.x << 16);
    f.y = __uint_as_float(u.x & 0xffff0000u);
    f.z = __uint_as_float(u.y << 16);
    f.w = __uint_as_float(u.y & 0xffff0000u);
    return f;
}

// ---------- bucket gather (bf16): one node/wave, 2 half-waves x 2 unroll ----
__global__ __launch_bounds__(256) void gather_bucket_bf16_kernel(
    const unsigned int* __restrict__ xh, const int* __restrict__ ei,
    const int* __restrict__ flag_p, const int* __restrict__ cursor,
    const int* __restrict__ csr_src, float* __restrict__ agg, int N, int E)
{
    int node = blockIdx.x * 4 + (threadIdx.x >> 6);
    if (node >= N) return;
    int lane = threadIdx.x & 63;
    int half = lane >> 5;
    int col = lane & 31;              // uint2 column: feats 4c..4c+3
    int deg = cursor[node];

    const uint2* x2 = reinterpret_cast<const uint2*>(xh);
    float4 a0 = make_float4(0.f, 0.f, 0.f, 0.f);
    float4 a1 = make_float4(0.f, 0.f, 0.f, 0.f);

    if (deg <= CAP) {
        int sv = (lane < deg) ? csr_src[node * CAP + lane] : 0;
        int i = 0;
        for (; i + 3 < deg; i += 4) {
            int e0 = __shfl(sv, i + half);
            int e1 = __shfl(sv, i + 2 + half);
            float4 v0 = bf16x4_to_f4(x2[(size_t)e0 * 32 + col]);
            float4 v1 = bf16x4_to_f4(x2[(size_t)e1 * 32 + col]);
            a0.x += v0.x; a0.y += v0.y; a0.z += v0.z; a0.w += v0.w;
            a1.x += v1.x; a1.y += v1.y; a1.z += v1.z; a1.w += v1.w;
        }
        for (; i + 1 < deg; i += 2) {
            int e0 = __shfl(sv, i + half);
            float4 v0 = bf16x4_to_f4(x2[(size_t)e0 * 32 + col]);
            a0.x += v0.x; a0.y += v0.y; a0.z += v0.z; a0.w += v0.w;
        }
        if (i < deg) {
            int e0 = __shfl(sv, i);
            if (half == 0) {
                float4 v = bf16x4_to_f4(x2[(size_t)e0 * 32 + col]);
                a0.x += v.x; a0.y += v.y; a0.z += v.z; a0.w += v.w;
            }
        }
    } else {
        // overflow (adversarial only): ballot-scan the full edge list
        int is64 = *flag_p;
        for (int base = 0; base < E; base += 64) {
            int e = base + lane;
            int s = 0, d = -1;
            if (e < E) load_edge(ei, is64, E, e, s, d);
            unsigned long long m = __ballot(d == node);
            while (m) {
                int i = __ffsll((long long)m) - 1;
                m &= m - 1;
                int sb = __shfl(s, i);
                float4 v = bf16x4_to_f4(x2[(size_t)sb * 32 + col]);
                if (half == 0) { a0.x += v.x; a0.y += v.y; a0.z += v.z; a0.w += v.w; }
            }
        }
    }
    a0.x += a1.x; a0.y += a1.y; a0.z += a1.z; a0.w += a1.w;
    a0.x += __shfl_xor(a0.x, 32);
    a0.y += __shfl_xor(a0.y, 32);
    a0.z += __shfl_xor(a0.z, 32);
    a0.w += __shfl_xor(a0.w, 32);
    if (half == 0)
        reinterpret_cast<float4*>(agg)[(size_t)node * 32 + col] = a0;
}

// ============ exact-CSR fallback chain (smaller ws) ============
__global__ __launch_bounds__(256) void hist_kernel(
    const int* __restrict__ ei, const int* __restrict__ flag_p,
    int* __restrict__ counts, int E)
{
    int e = blockIdx.x * 256 + threadIdx.x;
    if (e >= E) return;
    int s, d;
    load_edge(ei, *flag_p, E, e, s, d);
    atomicAdd(&counts[d], 1);
}

__global__ __launch_bounds__(256) void scan1_kernel(
    const int* __restrict__ counts, int* __restrict__ locoff,
    int* __restrict__ cursor, int* __restrict__ blocksums, int N)
{
    __shared__ int sh[256];
    int t = threadIdx.x;
    int i = blockIdx.x * 256 + t;
    int v = (i < N) ? counts[i] : 0;
    sh[t] = v;
    __syncthreads();
    int inc = v;
    #pragma unroll
    for (int ofs = 1; ofs < 256; ofs <<= 1) {
        int add = (t >= ofs) ? sh[t - ofs] : 0;
        __syncthreads();
        inc += add;
        sh[t] = inc;
        __syncthreads();
    }
    if (i < N) { locoff[i] = inc - v; cursor[i] = inc - v; }
    if (t == 255) blocksums[blockIdx.x] = inc;
}

__global__ __launch_bounds__(256) void scan2_kernel(
    int* __restrict__ blocksums, int* __restrict__ blockoffs, int nblk)
{
    __shared__ int sh[256];
    int t = threadIdx.x;
    int v = (t < nblk) ? blocksums[t] : 0;
    sh[t] = v;
    __syncthreads();
    int inc = v;
    #pragma unroll
    for (int ofs = 1; ofs < 256; ofs <<= 1) {
        int add = (t >= ofs) ? sh[t - ofs] : 0;
        __syncthreads();
        inc += add;
        sh[t] = inc;
        __syncthreads();
    }
    if (t < nblk) blockoffs[t] = inc - v;
}

__global__ __launch_bounds__(256) void position_kernel(
    const int* __restrict__ ei, const int* __restrict__ flag_p,
    int* __restrict__ cursor, const int* __restrict__ blockoffs,
    int* __restrict__ csr_src, int E)
{
    int e = blockIdx.x * 256 + threadIdx.x;
    if (e >= E) return;
    int s, d;
    load_edge(ei, *flag_p, E, e, s, d);
    int pos = atomicAdd(&cursor[d], 1) + blockoffs[d >> 8];
    csr_src[pos] = s;
}

__global__ __launch_bounds__(256) void gather_csr_bf16_kernel(
    const unsigned int* __restrict__ xh, const int* __restrict__ locoff,
    const int* __restrict__ blockoffs, const int* __restrict__ counts,
    const int* __restrict__ csr_src, float* __restrict__ agg, int N)
{
    int node = blockIdx.x * 4 + (threadIdx.x >> 6);
    if (node >= N) return;
    int lane = threadIdx.x & 63;
    int half = lane >> 5;
    int col = lane & 31;
    int start = locoff[node] + blockoffs[node >> 8];
    int deg = counts[node];

    const uint2* x2 = reinterpret_cast<const uint2*>(xh);
    float4 a0 = make_float4(0.f, 0.f, 0.f, 0.f);
    float4 a1 = make_float4(0.f, 0.f, 0.f, 0.f);

    for (int base = 0; base < deg; base += 64) {
        int rem = deg - base; if (rem > 64) rem = 64;
        int sv = (lane < rem) ? csr_src[start + base + lane] : 0;
        int i = 0;
        for (; i + 3 < rem; i += 4) {
            int e0 = __shfl(sv, i + half);
            int e1 = __shfl(sv, i + 2 + half);
            float4 v0 = bf16x4_to_f4(x2[(size_t)e0 * 32 + col]);
            float4 v1 = bf16x4_to_f4(x2[(size_t)e1 * 32 + col]);
            a0.x += v0.x; a0.y += v0.y; a0.z += v0.z; a0.w += v0.w;
            a1.x += v1.x; a1.y += v1.y; a1.z += v1.z; a1.w += v1.w;
        }
        for (; i + 1 < rem; i += 2) {
            int e0 = __shfl(sv, i + half);
            float4 v0 = bf16x4_to_f4(x2[(size_t)e0 * 32 + col]);
            a0.x += v0.x; a0.y += v0.y; a0.z += v0.z; a0.w += v0.w;
        }
        if (i < rem) {
            int e0 = __shfl(sv, i);
            if (half == 0) {
                float4 v = bf16x4_to_f4(x2[(size_t)e0 * 32 + col]);
                a0.x += v.x; a0.y += v.y; a0.z += v.z; a0.w += v.w;
            }
        }
    }
    a0.x += a1.x; a0.y += a1.y; a0.z += a1.z; a0.w += a1.w;
    a0.x += __shfl_xor(a0.x, 32);
    a0.y += __shfl_xor(a0.y, 32);
    a0.z += __shfl_xor(a0.z, 32);
    a0.w += __shfl_xor(a0.w, 32);
    if (half == 0)
        reinterpret_cast<float4*>(agg)[(size_t)node * 32 + col] = a0;
}

__global__ __launch_bounds__(256) void gather_csr_f32_kernel(
    const float* __restrict__ x, const int* __restrict__ locoff,
    const int* __restrict__ blockoffs, const int* __restrict__ counts,
    const int* __restrict__ csr_src, float* __restrict__ agg, int N)
{
    int node = blockIdx.x * 4 + (threadIdx.x >> 6);
    if (node >= N) return;
    int lane = threadIdx.x & 63;
    int half = lane >> 5;
    int col = lane & 31;
    int start = locoff[node] + blockoffs[node >> 8];
    int deg = counts[node];

    const float4* x4 = reinterpret_cast<const float4*>(x);
    float4 a0 = make_float4(0.f, 0.f, 0.f, 0.f);
    float4 a1 = make_float4(0.f, 0.f, 0.f, 0.f);

    for (int base = 0; base < deg; base += 64) {
        int rem = deg - base; if (rem > 64) rem = 64;
        int sv = (lane < rem) ? csr_src[start + base + lane] : 0;
        int i = 0;
        for (; i + 3 < rem; i += 4) {
            int e0 = __shfl(sv, i + half);
            int e1 = __shfl(sv, i + 2 + half);
            float4 v0 = x4[(size_t)e0 * 32 + col];
            float4 v1 = x4[(size_t)e1 * 32 + col];
            a0.x += v0.x; a0.y += v0.y; a0.z += v0.z; a0.w += v0.w;
            a1.x += v1.x; a1.y += v1.y; a1.z += v1.z; a1.w += v1.w;
        }
        for (; i + 1 < rem; i += 2) {
            int e0 = __shfl(sv, i + half);
            float4 v0 = x4[(size_t)e0 * 32 + col];
            a0.x += v0.x; a0.y += v0.y; a0.z += v0.z; a0.w += v0.w;
        }
        if (i < rem) {
            int e0 = __shfl(sv, i);
            if (half == 0) {
                float4 v = x4[(size_t)e0 * 32 + col];
                a0.x += v.x; a0.y += v.y; a0.z += v.z; a0.w += v.w;
            }
        }
    }
    a0.x += a1.x; a0.y += a1.y; a0.z += a1.z; a0.w += a1.w;
    a0.x += __shfl_xor(a0.x, 32);
    a0.y += __shfl_xor(a0.y, 32);
    a0.z += __shfl_xor(a0.z, 32);
    a0.w += __shfl_xor(a0.w, 32);
    if (half == 0)
        reinterpret_cast<float4*>(agg)[(size_t)node * 32 + col] = a0;
}

// ---------- last-resort: atomic scatter ----------
__global__ __launch_bounds__(256) void scatter_kernel(
    const float* __restrict__ x, const int* __restrict__ ei,
    const int* __restrict__ flag_p, float* __restrict__ agg, int E)
{
    int tid = blockIdx.x * 256 + threadIdx.x;
    int e = tid >> 5;
    if (e >= E) return;
    int c = (tid & 31) << 2;
    int s, d;
    load_edge(ei, *flag_p, E, e, s, d);
    float4 v = *reinterpret_cast<const float4*>(x + (size_t)s * F + c);
    float* o = agg + (size_t)d * F + c;
    unsafeAtomicAdd(o + 0, v.x);
    unsafeAtomicAdd(o + 1, v.y);
    unsafeAtomicAdd(o + 2, v.z);
    unsafeAtomicAdd(o + 3, v.w);
}

// ---------- in-place GEMM: io = io @ W + bias ----------
__global__ __launch_bounds__(256) void gemm_kernel(
    float* __restrict__ io, const float* __restrict__ W,
    const float* __restrict__ bias, int N)
{
    __shared__ float sA[TR * LDA];
    __shared__ float sW[KC * LDW];
    const int t = threadIdx.x;
    const int row0 = blockIdx.x * TR;
    const int g = t & 7;
    const int r = t >> 3;

    float acc[2][16];
    #pragma unroll
    for (int i = 0; i < 2; ++i)
        #pragma unroll
        for (int j = 0; j < 16; ++j) acc[i][j] = 0.0f;

    for (int kc = 0; kc < F; kc += KC) {
        #pragma unroll
        for (int u = 0; u < 2; ++u) {
            int idx = u * 256 + t;
            int row = idx >> 3;
            int k4 = (idx & 7) * 4;
            int grow = row0 + row;
            float4 v = (grow < N)
                ? *reinterpret_cast<const float4*>(io + (size_t)grow * F + kc + k4)
                : make_float4(0.f, 0.f, 0.f, 0.f);
            *reinterpret_cast<float4*>(&sA[row * LDA + k4]) = v;
        }
        #pragma unroll
        for (int u = 0; u < 4; ++u) {
            int idx = u * 256 + t;
            int kk = idx >> 5;
            int f4 = (idx & 31) * 4;
            float4 v = *reinterpret_cast<const float4*>(W + (size_t)(kc + kk) * F + f4);
            int chunk = f4 >> 4;
            int within = f4 & 15;
            *reinterpret_cast<float4*>(&sW[kk * LDW + chunk * 20 + within]) = v;
        }
        __syncthreads();

        #pragma unroll 8
        for (int kk = 0; kk < KC; ++kk) {
            const float* wp = &sW[kk * LDW + g * 20];
            const float4 w0 = *reinterpret_cast<const float4*>(wp + 0);
            const float4 w1 = *reinterpret_cast<const float4*>(wp + 4);
            const float4 w2 = *reinterpret_cast<const float4*>(wp + 8);
            const float4 w3 = *reinterpret_cast<const float4*>(wp + 12);
            #pragma unroll
            for (int i = 0; i < 2; ++i) {
                const float xv = sA[(r * 2 + i) * LDA + kk];
                acc[i][0]  += xv * w0.x;  acc[i][1]  += xv * w0.y;
                acc[i][2]  += xv * w0.z;  acc[i][3]  += xv * w0.w;
                acc[i][4]  += xv * w1.x;  acc[i][5]  += xv * w1.y;
                acc[i][6]  += xv * w1.z;  acc[i][7]  += xv * w1.w;
                acc[i][8]  += xv * w2.x;  acc[i][9]  += xv * w2.y;
                acc[i][10] += xv * w2.z;  acc[i][11] += xv * w2.w;
                acc[i][12] += xv * w3.x;  acc[i][13] += xv * w3.y;
                acc[i][14] += xv * w3.z;  acc[i][15] += xv * w3.w;
            }
        }
        __syncthreads();
    }

    float bv[16];
    #pragma unroll
    for (int j = 0; j < 16; ++j) bv[j] = bias[g * 16 + j];
    #pragma unroll
    for (int i = 0; i < 2; ++i) {
        int row = row0 + r * 2 + i;
        if (row < N) {
            float* o = io + (size_t)row * F + g * 16;
            #pragma unroll
            for (int j4 = 0; j4 < 4; ++j4) {
                float4 v;
                v.x = acc[i][j4 * 4 + 0] + bv[j4 * 4 + 0];
                v.y = acc[i][j4 * 4 + 1] + bv[j4 * 4 + 1];
                v.z = acc[i][j4 * 4 + 2] + bv[j4 * 4 + 2];
                v.w = acc[i][j4 * 4 + 3] + bv[j4 * 4 + 3];
                *reinterpret_cast<float4*>(o + j4 * 4) = v;
            }
        }
    }
}

extern "C" void kernel_launch(void* const* d_in, const int* in_sizes, int n_in,
                              void* d_out, int out_size, void* d_ws, size_t ws_size,
                              hipStream_t stream) {
    const float* x  = (const float*)d_in[0];
    const int*   ei = (const int*)d_in[1];
    const float* W2 = (const float*)d_in[5];
    const float* b2 = (const float*)d_in[6];
    float* out = (float*)d_out;

    const int N = in_sizes[0] / F;   // 50000
    const int E = in_sizes[2];       // 600000
    const int nblk = (N + 255) / 256;
    const int M = N * (F / 2);       // bf16-pair element count
    const int eblk = (E + 255) / 256;

    int* ws = (int*)d_ws;
    // tier A layout: flag[16], cursor[N], csr_src[N*CAP], xh[M]
    size_t needA = (size_t)(16 + N + N * CAP + M) * sizeof(int);
    // tier B/C layout: flag[16], counts[N], locoff[N], cursor[N],
    //                  blocksums[nblk], blockoffs[nblk], csr_src[E], (xh[M])
    size_t needC = (size_t)(16 + 3 * N + 2 * nblk + E) * sizeof(int);
    size_t needB = needC + (size_t)M * sizeof(int);

    if (ws_size >= needA) {
        int* flag    = ws;
        int* cursor  = flag + 16;
        int* csr_src = cursor + N;
        unsigned int* xh = (unsigned int*)(csr_src + (size_t)N * CAP);

        int iblk = ((M > N ? M : N) + 255) / 256;
        init_kernel<<<iblk, 256, 0, stream>>>(ei, x, flag, cursor, xh, N, M);
        position_bucket_kernel<<<eblk, 256, 0, stream>>>(ei, flag, cursor, csr_src, E);
        gather_bucket_bf16_kernel<<<(N + 3) / 4, 256, 0, stream>>>(
            xh, ei, flag, cursor, csr_src, out, N, E);
    } else if (ws_size >= needC) {
        int* flag      = ws;
        int* counts    = flag + 16;
        int* locoff    = counts + N;
        int* cursor    = locoff + N;
        int* blocksums = cursor + N;
        int* blockoffs = blocksums + nblk;
        int* csr_src   = blockoffs + nblk;
        unsigned int* xh = (unsigned int*)(csr_src + E);
        int do_bf16 = (ws_size >= needB) ? 1 : 0;
        int Mx = do_bf16 ? M : 0;

        int iblk = (((Mx > N ? Mx : N)) + 255) / 256;
        init_kernel<<<iblk, 256, 0, stream>>>(ei, x, flag, counts, xh, N, Mx);
        hist_kernel<<<eblk, 256, 0, stream>>>(ei, flag, counts, E);
        scan1_kernel<<<nblk, 256, 0, stream>>>(counts, locoff, cursor, blocksums, N);
        scan2_kernel<<<1, 256, 0, stream>>>(blocksums, blockoffs, nblk);
        position_kernel<<<eblk, 256, 0, stream>>>(ei, flag, cursor, blockoffs, csr_src, E);
        if (do_bf16)
            gather_csr_bf16_kernel<<<(N + 3) / 4, 256, 0, stream>>>(
                xh, locoff, blockoffs, counts, csr_src, out, N);
        else
            gather_csr_f32_kernel<<<(N + 3) / 4, 256, 0, stream>>>(
                x, locoff, blockoffs, counts, csr_src, out, N);
    } else {
        int* flag = ws;
        init_kernel<<<1, 64, 0, stream>>>(ei, x, flag, flag + 16, nullptr, 0, 0);
        hipMemsetAsync(out, 0, (size_t)N * F * sizeof(float), stream);
        scatter_kernel<<<(E * 32 + 255) / 256, 256, 0, stream>>>(x, ei, flag, out, E);
    }

    gemm_kernel<<<(N + TR - 1) / TR, 256, 0, stream>>>(out, W2, b2, N);
}